// Round 1
// baseline (340.034 us; speedup 1.0000x reference)
//
#include <hip/hip_runtime.h>

// out[b,i,f] = X[b,0,i,i,f] + sum_j A[b,i,j] * (X[b,1,i,j,f]+X[b,2,i,j,f]+X[b,3,i,j,f])
// A: (4,256,256) f32, X: (4,4,256,256,64) f32, out: (4,256,64) f32

constexpr int N   = 256;
constexpr int F   = 64;
constexpr int F4  = F / 4;   // 16 float4 per row
constexpr int KP1 = 4;

__global__ __launch_bounds__(256) void gnn_kernel(const float* __restrict__ A,
                                                  const float* __restrict__ X,
                                                  float* __restrict__ out) {
    // one block per (b, i)
    const int bi = blockIdx.x;          // 0..1023
    const int b  = bi >> 8;
    const int i  = bi & (N - 1);
    const int t  = threadIdx.x;         // 0..255
    const int f4 = t & (F4 - 1);        // 0..15
    const int j0 = t >> 4;              // 0..15

    __shared__ float  sA[N];
    __shared__ float4 sAcc[256];

    // stage A row into LDS (1 KiB, one coalesced load)
    sA[t] = A[(size_t)b * N * N + (size_t)i * N + t];
    __syncthreads();

    const size_t kstride = (size_t)N * N * F;         // elements per hop slab
    const size_t bstride = (size_t)KP1 * kstride;
    const size_t istride = (size_t)N * F;             // one (i) row: 256 j x 64 f

    const float* baseRow = X + (size_t)b * bstride + (size_t)i * istride;
    const float4* __restrict__ X1 = (const float4*)(baseRow + 1 * kstride);
    const float4* __restrict__ X2 = (const float4*)(baseRow + 2 * kstride);
    const float4* __restrict__ X3 = (const float4*)(baseRow + 3 * kstride);

    float4 acc = make_float4(0.f, 0.f, 0.f, 0.f);

#pragma unroll 4
    for (int jj = 0; jj < N / 16; ++jj) {
        const int j   = j0 + jj * 16;
        const int idx = j * F4 + f4;
        const float a = sA[j];
        const float4 x1 = X1[idx];
        const float4 x2 = X2[idx];
        const float4 x3 = X3[idx];
        acc.x += a * (x1.x + x2.x + x3.x);
        acc.y += a * (x1.y + x2.y + x3.y);
        acc.z += a * (x1.z + x2.z + x3.z);
        acc.w += a * (x1.w + x2.w + x3.w);
    }

    sAcc[t] = acc;
    __syncthreads();

    if (t < F4) {
        float4 r = make_float4(0.f, 0.f, 0.f, 0.f);
#pragma unroll
        for (int g = 0; g < 16; ++g) {
            const float4 v = sAcc[t + g * F4];
            r.x += v.x; r.y += v.y; r.z += v.z; r.w += v.w;
        }
        // hop-0 identity term: diagonal X[b,0,i,i,:]
        const float4* Xd = (const float4*)(baseRow + (size_t)i * F);
        const float4 d = Xd[t];
        r.x += d.x; r.y += d.y; r.z += d.z; r.w += d.w;
        ((float4*)(out + (size_t)b * N * F + (size_t)i * F))[t] = r;
    }
}

extern "C" void kernel_launch(void* const* d_in, const int* in_sizes, int n_in,
                              void* d_out, int out_size, void* d_ws, size_t ws_size,
                              hipStream_t stream) {
    const float* A = (const float*)d_in[0];
    const float* X = (const float*)d_in[1];
    float* out = (float*)d_out;
    const int batch = 4;
    dim3 grid(batch * N);
    dim3 block(256);
    gnn_kernel<<<grid, block, 0, stream>>>(A, X, out);
}